// Round 1
// baseline (117.107 us; speedup 1.0000x reference)
//
#include <hip/hip_runtime.h>

// Problem: y = x * exp(S)[None,:]  (B=65536, D=1024, f32)
//          det_out = original_det + sum(S)
// d_out layout: [ y (B*D f32) | det_out (B f32) ]
// d_ws layout:  [ expS (D f32) | log_det (1 f32) ]

// ---- Kernel A: expS table + log_det reduction (1 block) ----
__global__ __launch_bounds__(1024) void prep_kernel(const float* __restrict__ S,
                                                    float* __restrict__ ws,  // [D expS][1 logdet]
                                                    int D) {
    __shared__ float red[1024];
    int i = threadIdx.x;
    float s = (i < D) ? S[i] : 0.0f;
    if (i < D) ws[i] = expf(s);
    red[i] = s;
    __syncthreads();
    for (int off = 512; off > 0; off >>= 1) {
        if (i < off) red[i] += red[i + off];
        __syncthreads();
    }
    if (i == 0) ws[D] = red[0];
}

// ---- Kernel B: y = x * expS (vectorized float4, grid-stride) ----
// Assumes D % 4 == 0 and (D/4) is a power of two (D=1024 -> 256 float4/row).
__global__ __launch_bounds__(256) void scale_kernel(const float4* __restrict__ x,
                                                    const float* __restrict__ ws,
                                                    float4* __restrict__ y,
                                                    size_t nvec, unsigned vmask) {
    __shared__ float4 es[256];
    const float4* expS4 = (const float4*)ws;
    if (threadIdx.x < 256) es[threadIdx.x] = expS4[threadIdx.x & vmask];
    __syncthreads();
    size_t stride = (size_t)gridDim.x * blockDim.x;
    for (size_t v = (size_t)blockIdx.x * blockDim.x + threadIdx.x; v < nvec; v += stride) {
        float4 xv = x[v];
        float4 e  = es[(unsigned)v & vmask];
        float4 o;
        o.x = xv.x * e.x;
        o.y = xv.y * e.y;
        o.z = xv.z * e.z;
        o.w = xv.w * e.w;
        y[v] = o;
    }
}

// ---- Kernel C: det_out = original_det + log_det ----
__global__ __launch_bounds__(256) void det_kernel(const float4* __restrict__ det,
                                                  const float* __restrict__ logdet_p,
                                                  float4* __restrict__ out,
                                                  int nvec) {
    int i = blockIdx.x * blockDim.x + threadIdx.x;
    if (i < nvec) {
        float ld = *logdet_p;
        float4 d = det[i];
        float4 o;
        o.x = d.x + ld;
        o.y = d.y + ld;
        o.z = d.z + ld;
        o.w = d.w + ld;
        out[i] = o;
    }
}

extern "C" void kernel_launch(void* const* d_in, const int* in_sizes, int n_in,
                              void* d_out, int out_size, void* d_ws, size_t ws_size,
                              hipStream_t stream) {
    const float* x   = (const float*)d_in[0];
    const float* det = (const float*)d_in[1];
    const float* S   = (const float*)d_in[2];

    const int xN = in_sizes[0];      // B*D
    const int B  = in_sizes[1];      // 65536
    const int D  = in_sizes[2];      // 1024

    float* y_out   = (float*)d_out;
    float* det_out = (float*)d_out + (size_t)xN;
    float* ws      = (float*)d_ws;   // [D expS][1 logdet]

    // A: expS + logdet (single block covers D<=1024)
    prep_kernel<<<1, 1024, 0, stream>>>(S, ws, D);

    // B: main scaling, float4 vectorized
    size_t nvec = (size_t)xN / 4;
    unsigned vpr = (unsigned)(D / 4);      // float4 per row (256), power of two
    unsigned vmask = vpr - 1;
    int blocks = 4096;                     // grid-stride; 256 CU * 16 blocks
    scale_kernel<<<blocks, 256, 0, stream>>>((const float4*)x, ws, (float4*)y_out,
                                             nvec, vmask);

    // C: det add
    int dvec = B / 4;
    det_kernel<<<(dvec + 255) / 256, 256, 0, stream>>>((const float4*)det, ws + D,
                                                       (float4*)det_out, dvec);
}

// Round 3
// 94.071 us; speedup vs baseline: 1.2449x; 1.2449x over previous
//
#include <hip/hip_runtime.h>

// Problem: y = x * exp(S)[None,:]  (B=65536, D=1024, f32)
//          det_out = original_det + sum(S)
// d_out layout: [ y (B*D f32) | det_out (B f32) ]
//
// Single fused kernel. blockDim.x == D/4 == 256, so with a grid stride that is
// a multiple of 256 float4s, thread t only ever touches column block t of each
// row -> its exp(S) factor is 4 registers, no LDS on the hot path.
//
// Use a native clang vector type: __builtin_nontemporal_load/store rejects
// HIP_vector_type structs but accepts ext_vector_type.

typedef float f32x4 __attribute__((ext_vector_type(4)));

__global__ __launch_bounds__(256) void fused_kernel(
    const f32x4* __restrict__ x,
    const f32x4* __restrict__ det,
    const f32x4* __restrict__ S4,      // D/4 float4
    f32x4* __restrict__ y,
    f32x4* __restrict__ det_out,
    size_t nvec,                       // B*D/4
    int    dvec)                       // B/4
{
    const int tid = threadIdx.x;

    // --- per-thread exp(S) factor (thread t owns columns 4t..4t+3) ---
    f32x4 s4 = S4[tid];
    f32x4 e4;
    e4.x = expf(s4.x);
    e4.y = expf(s4.y);
    e4.z = expf(s4.z);
    e4.w = expf(s4.w);

    // --- block-redundant log_det = sum(S) (cheap: ~10 shuffle+add) ---
    __shared__ float red[4];
    float local = s4.x + s4.y + s4.z + s4.w;
    for (int off = 32; off > 0; off >>= 1)
        local += __shfl_down(local, off, 64);
    if ((tid & 63) == 0) red[tid >> 6] = local;
    __syncthreads();
    const float log_det = red[0] + red[1] + red[2] + red[3];

    // --- main stream: y = x * e4 ---
    const size_t stride = (size_t)gridDim.x * 256;   // multiple of 256
    for (size_t v = (size_t)blockIdx.x * 256 + tid; v < nvec; v += stride) {
        f32x4 xv = __builtin_nontemporal_load(&x[v]);
        f32x4 o  = xv * e4;
        __builtin_nontemporal_store(o, &y[v]);
    }

    // --- det tail: det_out = det + log_det (256 KB r + 256 KB w) ---
    for (size_t i = (size_t)blockIdx.x * 256 + tid; i < (size_t)dvec; i += stride) {
        f32x4 d = __builtin_nontemporal_load(&det[i]);
        f32x4 o = d + log_det;
        __builtin_nontemporal_store(o, &det_out[i]);
    }
}

extern "C" void kernel_launch(void* const* d_in, const int* in_sizes, int n_in,
                              void* d_out, int out_size, void* d_ws, size_t ws_size,
                              hipStream_t stream) {
    const float* x   = (const float*)d_in[0];
    const float* det = (const float*)d_in[1];
    const float* S   = (const float*)d_in[2];

    const int xN = in_sizes[0];      // B*D = 67108864
    const int B  = in_sizes[1];      // 65536

    float* y_out   = (float*)d_out;
    float* det_out = (float*)d_out + (size_t)xN;

    size_t nvec = (size_t)xN / 4;    // 16,777,216 float4
    int    dvec = B / 4;             // 16,384 float4

    // 8192 blocks x 256 threads = 2M lanes = 32 waves/CU; 8 float4 per lane.
    int blocks = 8192;

    fused_kernel<<<blocks, 256, 0, stream>>>(
        (const f32x4*)x, (const f32x4*)det, (const f32x4*)S,
        (f32x4*)y_out, (f32x4*)det_out, nvec, dvec);
}